// Round 6
// baseline (412.247 us; speedup 1.0000x reference)
//
#include <hip/hip_runtime.h>
#include <math.h>

#define EDIM 768
#define NSEQ 1024
#define NB 8
#define NH 12
#define DH 64

typedef __attribute__((ext_vector_type(8))) short bh8;       // 8 bf16 (4 VGPRs) MFMA frag
typedef __attribute__((ext_vector_type(4))) float f4;        // MFMA acc
typedef __attribute__((ext_vector_type(8))) unsigned short us8;
typedef __attribute__((ext_vector_type(4))) unsigned short us4;

#define MFMA(a, b, c) __builtin_amdgcn_mfma_f32_16x16x32_bf16((bh8)(a), (bh8)(b), (c), 0, 0, 0)

__device__ __forceinline__ unsigned short f2bf(float x) {
    union { float f; unsigned u; } v; v.f = x;
    unsigned r = v.u + 0x7fff + ((v.u >> 16) & 1);   // round-to-nearest-even
    return (unsigned short)(r >> 16);
}
__device__ __forceinline__ float bf2f(unsigned short b) {
    union { float f; unsigned u; } v; v.u = ((unsigned)b) << 16;
    return v.f;
}

// ---------------------------------------------------------------------------
// emb fp32 -> hi/lo bf16
// ---------------------------------------------------------------------------
__global__ __launch_bounds__(256)
void conv_emb(const float* __restrict__ E, unsigned short* __restrict__ Eh,
              unsigned short* __restrict__ El)
{
    size_t idx = ((size_t)blockIdx.x * 256 + threadIdx.x) * 4;
    float4 v = *(const float4*)&E[idx];
    us4 h, l;
    h.x = f2bf(v.x); l.x = f2bf(v.x - bf2f(h.x));
    h.y = f2bf(v.y); l.y = f2bf(v.y - bf2f(h.y));
    h.z = f2bf(v.z); l.z = f2bf(v.z - bf2f(h.z));
    h.w = f2bf(v.w); l.w = f2bf(v.w - bf2f(h.w));
    *(us4*)&Eh[idx] = h;
    *(us4*)&El[idx] = l;
}

// ---------------------------------------------------------------------------
// W [768k][768n] fp32 -> Wt [768n][768k] hi/lo bf16 (transposed).
// ---------------------------------------------------------------------------
__global__ __launch_bounds__(256)
void conv_w(const float* __restrict__ W0, const float* __restrict__ W1,
            const float* __restrict__ W2, const float* __restrict__ W3,
            unsigned short* __restrict__ Wbase)
{
    const int z = blockIdx.z;
    const float* __restrict__ W = (z == 0) ? W0 : (z == 1) ? W1 : (z == 2) ? W2 : W3;
    unsigned short* __restrict__ Wh = Wbase + (size_t)z * 2 * (EDIM * EDIM);
    unsigned short* __restrict__ Wl = Wh + (EDIM * EDIM);

    __shared__ float T[64][65];
    const int t = threadIdx.x;
    const int n0 = blockIdx.x * 64, k0 = blockIdx.y * 64;

#pragma unroll
    for (int rr = 0; rr < 4; rr++) {
        int row = rr * 16 + (t >> 4);      // k within tile
        int c4  = (t & 15) * 4;            // n within tile
        float4 v = *(const float4*)&W[(size_t)(k0 + row) * EDIM + n0 + c4];
        T[row][c4 + 0] = v.x; T[row][c4 + 1] = v.y;
        T[row][c4 + 2] = v.z; T[row][c4 + 3] = v.w;
    }
    __syncthreads();
#pragma unroll
    for (int rr = 0; rr < 4; rr++) {
        int nn = rr * 16 + (t >> 4);       // n within tile
        int k4 = (t & 15) * 4;             // k within tile
        us4 h, l;
        float v0 = T[k4 + 0][nn], v1 = T[k4 + 1][nn],
              v2 = T[k4 + 2][nn], v3 = T[k4 + 3][nn];
        h.x = f2bf(v0); l.x = f2bf(v0 - bf2f(h.x));
        h.y = f2bf(v1); l.y = f2bf(v1 - bf2f(h.y));
        h.z = f2bf(v2); l.z = f2bf(v2 - bf2f(h.z));
        h.w = f2bf(v3); l.w = f2bf(v3 - bf2f(h.w));
        size_t o = (size_t)(n0 + nn) * EDIM + k0 + k4;
        *(us4*)&Wh[o] = h;
        *(us4*)&Wl[o] = l;
    }
}

// ---------------------------------------------------------------------------
// QKV projection, split-bf16 MFMA, quad-major LDS, XCD-swizzled.
// z=0 (Q), z=1 (K): 3-term hi/lo. z=2 (V): 1-term.
// ---------------------------------------------------------------------------
__global__ __launch_bounds__(256)
void qkv_gemm(const unsigned short* __restrict__ Eh, const unsigned short* __restrict__ El,
              const unsigned short* __restrict__ Wbase,
              unsigned short* __restrict__ Qh, unsigned short* __restrict__ Ql,
              unsigned short* __restrict__ Kh, unsigned short* __restrict__ Kl,
              unsigned short* __restrict__ Vt)
{
    // bid in [0,1152): xcd = bid&7 owns m-strips [8*xcd, 8*xcd+8)
    const int bid = blockIdx.x;
    const int xcd = bid & 7, j = bid >> 3;        // j in [0,144)
    const int mblk = xcd * 8 + (j / 18);          // 0..63
    const int rest = j % 18;
    const int nblk = rest % 6, z = rest / 6;

    const unsigned short* __restrict__ Wh = Wbase + (size_t)z * 2 * (EDIM * EDIM);
    const unsigned short* __restrict__ Wl = Wh + (EDIM * EDIM);

    __shared__ unsigned short Ahq[4][128][8], Alq[4][128][8];
    __shared__ unsigned short Bhq[4][128][8], Blq[4][128][8];

    const int t = threadIdx.x;
    const int wave = t >> 6, lane = t & 63;
    const int quad = lane >> 4, l16 = lane & 15;
    const int wm = (wave >> 1) * 64, wn = (wave & 1) * 64;
    const int m0 = mblk * 128, n0 = nblk * 128;

    const int sr = t >> 1, q0 = (t & 1) * 2;   // staging: row, first quad

    f4 acc[4][4];
#pragma unroll
    for (int i = 0; i < 4; i++)
#pragma unroll
        for (int j2 = 0; j2 < 4; j2++) acc[i][j2] = (f4){0.f, 0.f, 0.f, 0.f};

    for (int k0 = 0; k0 < EDIM; k0 += 32) {
        const size_t ao = (size_t)(m0 + sr) * EDIM + k0 + q0 * 8;
        const size_t bo = (size_t)(n0 + sr) * EDIM + k0 + q0 * 8;
        us8 a0 = *(const us8*)&Eh[ao], a1 = *(const us8*)&Eh[ao + 8];
        us8 b0 = *(const us8*)&Wh[bo], b1 = *(const us8*)&Wh[bo + 8];
        us8 a2, a3, b2, b3;
        if (z != 2) {
            a2 = *(const us8*)&El[ao]; a3 = *(const us8*)&El[ao + 8];
            b2 = *(const us8*)&Wl[bo]; b3 = *(const us8*)&Wl[bo + 8];
        }
        __syncthreads();
        *(us8*)&Ahq[q0][sr][0] = a0; *(us8*)&Ahq[q0 + 1][sr][0] = a1;
        *(us8*)&Bhq[q0][sr][0] = b0; *(us8*)&Bhq[q0 + 1][sr][0] = b1;
        if (z != 2) {
            *(us8*)&Alq[q0][sr][0] = a2; *(us8*)&Alq[q0 + 1][sr][0] = a3;
            *(us8*)&Blq[q0][sr][0] = b2; *(us8*)&Blq[q0 + 1][sr][0] = b3;
        }
        __syncthreads();

        bh8 aH[4], bH[4];
#pragma unroll
        for (int mt = 0; mt < 4; mt++)
            aH[mt] = *(const bh8*)&Ahq[quad][wm + mt * 16 + l16][0];
#pragma unroll
        for (int nt = 0; nt < 4; nt++)
            bH[nt] = *(const bh8*)&Bhq[quad][wn + nt * 16 + l16][0];

        if (z != 2) {
            bh8 aL[4], bL[4];
#pragma unroll
            for (int mt = 0; mt < 4; mt++)
                aL[mt] = *(const bh8*)&Alq[quad][wm + mt * 16 + l16][0];
#pragma unroll
            for (int nt = 0; nt < 4; nt++)
                bL[nt] = *(const bh8*)&Blq[quad][wn + nt * 16 + l16][0];
#pragma unroll
            for (int mt = 0; mt < 4; mt++)
#pragma unroll
                for (int nt = 0; nt < 4; nt++) {
                    acc[mt][nt] = MFMA(aH[mt], bH[nt], acc[mt][nt]);
                    acc[mt][nt] = MFMA(aH[mt], bL[nt], acc[mt][nt]);
                    acc[mt][nt] = MFMA(aL[mt], bH[nt], acc[mt][nt]);
                }
        } else {
#pragma unroll
            for (int mt = 0; mt < 4; mt++)
#pragma unroll
                for (int nt = 0; nt < 4; nt++)
                    acc[mt][nt] = MFMA(aH[mt], bH[nt], acc[mt][nt]);
        }
    }

    // epilogue: C/D layout col=lane&15, row=quad*4+reg
#pragma unroll
    for (int mt = 0; mt < 4; mt++)
#pragma unroll
        for (int nt = 0; nt < 4; nt++)
#pragma unroll
            for (int r = 0; r < 4; r++) {
                int row = m0 + wm + mt * 16 + quad * 4 + r;
                int col = n0 + wn + nt * 16 + l16;
                float v = acc[mt][nt][r];
                if (z == 2) {
                    int bb = row >> 10, nr = row & 1023;
                    int g = nr * 12 + (col >> 6);          // 768 = 12*64
                    int hh = g >> 10, key = g & 1023, dim = col & 63;
                    Vt[(((size_t)(bb * NH + hh)) * DH + dim) * NSEQ + key] = f2bf(v);
                } else {
                    unsigned short h = f2bf(v);
                    unsigned short l = f2bf(v - bf2f(h));
                    size_t o = (size_t)row * EDIM + col;
                    if (z == 0) { Qh[o] = h; Ql[o] = l; }
                    else        { Kh[o] = h; Kl[o] = l; }
                }
            }
}

// ---------------------------------------------------------------------------
// Flash attention, MFMA, XCD-swizzled (cluster by head for bias L2 locality).
// Occupancy fix: Q is staged through the K LDS buffers (frags live in regs),
// cutting LDS 54->36 KB => 4 blocks/CU. Ps row stride 68 so the 16 b16
// P-writes/lane are 2-way (free) instead of 4-way.
// ---------------------------------------------------------------------------
__global__ __launch_bounds__(256)
void attn_mfma(const unsigned short* __restrict__ Qh, const unsigned short* __restrict__ Ql,
               const unsigned short* __restrict__ Kh, const unsigned short* __restrict__ Kl,
               const unsigned short* __restrict__ Vt, const float* __restrict__ Bm,
               unsigned short* __restrict__ Hc)
{
    // bid in [0,1536): xcd = bid&7; 12 (h,b) combos per xcd, clustered by h.
    const int bid = blockIdx.x;
    const int xcd = bid & 7, j = bid >> 3;        // j in [0,192)
    const int combo = xcd * 12 + (j >> 4);        // 0..95, consecutive = same h
    const int rt = j & 15;
    const int h = combo >> 3, b = combo & 7;
    const int r0 = rt * 64;

    __shared__ unsigned short Khs[64][72], Kls[64][72];   // also Q staging
    __shared__ unsigned short Vts[64][72];                // [dim][key]
    __shared__ unsigned short Ps[4][16][68];              // stride 68: see header

    const int t = threadIdx.x;
    const int wave = t >> 6, lane = t & 63;
    const int quad = lane >> 4, l16 = lane & 15;
    const int wr = wave * 16;

    const int srow = t >> 2, sseg = (t & 3) * 16;

    const size_t hb = (size_t)b * (NSEQ * EDIM) + (size_t)h * (NSEQ * DH);
    const size_t vb = (((size_t)(b * NH + h)) * DH) * NSEQ;

    // ---- stage Q through the K buffers, pull frags to registers ----
    bh8 qfh[2], qfl[2];
    {
        const size_t qo = hb + (size_t)(r0 + srow) * DH + sseg;
        us8 q0 = *(const us8*)&Qh[qo], q1 = *(const us8*)&Qh[qo + 8];
        us8 q2 = *(const us8*)&Ql[qo], q3 = *(const us8*)&Ql[qo + 8];
        *(us8*)&Khs[srow][sseg] = q0; *(us8*)&Khs[srow][sseg + 8] = q1;
        *(us8*)&Kls[srow][sseg] = q2; *(us8*)&Kls[srow][sseg + 8] = q3;
        __syncthreads();
#pragma unroll
        for (int ks = 0; ks < 2; ks++) {
            qfh[ks] = *(const bh8*)&Khs[wr + l16][ks * 32 + quad * 8];
            qfl[ks] = *(const bh8*)&Kls[wr + l16][ks * 32 + quad * 8];
        }
    }

    float m[4] = {-3e38f, -3e38f, -3e38f, -3e38f};
    float lsum[4] = {0.f, 0.f, 0.f, 0.f};
    f4 o[4];
#pragma unroll
    for (int dt = 0; dt < 4; dt++) o[dt] = (f4){0.f, 0.f, 0.f, 0.f};

    const float* bb = Bm + ((size_t)h << 20) + ((size_t)(r0 + wr + quad * 4) << 10) + l16;

    for (int kt = 0; kt < 16; kt++) {
        const int c0 = kt * 64;
        const size_t ko = hb + (size_t)(c0 + srow) * DH + sseg;
        const size_t vo = vb + (size_t)srow * NSEQ + c0 + sseg;
        us8 k0v = *(const us8*)&Kh[ko], k1v = *(const us8*)&Kh[ko + 8];
        us8 k2v = *(const us8*)&Kl[ko], k3v = *(const us8*)&Kl[ko + 8];
        us8 v0v = *(const us8*)&Vt[vo], v1v = *(const us8*)&Vt[vo + 8];
        __syncthreads();   // previous tile consumed (and Q frags read, kt=0)
        *(us8*)&Khs[srow][sseg] = k0v; *(us8*)&Khs[srow][sseg + 8] = k1v;
        *(us8*)&Kls[srow][sseg] = k2v; *(us8*)&Kls[srow][sseg + 8] = k3v;
        *(us8*)&Vts[srow][sseg] = v0v; *(us8*)&Vts[srow][sseg + 8] = v1v;
        __syncthreads();

        // ---- scores ----
        f4 s[4];
#pragma unroll
        for (int ct = 0; ct < 4; ct++) {
            bh8 kh0 = *(const bh8*)&Khs[ct * 16 + l16][quad * 8];
            bh8 kh1 = *(const bh8*)&Khs[ct * 16 + l16][32 + quad * 8];
            bh8 kl0 = *(const bh8*)&Kls[ct * 16 + l16][quad * 8];
            bh8 kl1 = *(const bh8*)&Kls[ct * 16 + l16][32 + quad * 8];
            f4 a = (f4){0.f, 0.f, 0.f, 0.f};
            a = MFMA(qfh[0], kh0, a); a = MFMA(qfh[1], kh1, a);
            a = MFMA(qfl[0], kh0, a); a = MFMA(qfl[1], kh1, a);
            a = MFMA(qfh[0], kl0, a); a = MFMA(qfh[1], kl1, a);
            s[ct] = a;
        }
#pragma unroll
        for (int ct = 0; ct < 4; ct++)
#pragma unroll
            for (int r = 0; r < 4; r++)
                s[ct][r] = fmaf(s[ct][r], 0.125f, bb[(size_t)r * NSEQ + c0 + ct * 16]);

        // ---- online softmax ----
        float alpha[4];
#pragma unroll
        for (int r = 0; r < 4; r++) {
            float mx = fmaxf(fmaxf(s[0][r], s[1][r]), fmaxf(s[2][r], s[3][r]));
            mx = fmaxf(mx, __shfl_xor(mx, 1));
            mx = fmaxf(mx, __shfl_xor(mx, 2));
            mx = fmaxf(mx, __shfl_xor(mx, 4));
            mx = fmaxf(mx, __shfl_xor(mx, 8));
            float mn = fmaxf(m[r], mx);
            alpha[r] = __expf(m[r] - mn);
            m[r] = mn;
        }
#pragma unroll
        for (int ct = 0; ct < 4; ct++)
#pragma unroll
            for (int r = 0; r < 4; r++)
                s[ct][r] = __expf(s[ct][r] - m[r]);
#pragma unroll
        for (int r = 0; r < 4; r++) {
            float ls = s[0][r] + s[1][r] + s[2][r] + s[3][r];
            ls += __shfl_xor(ls, 1);
            ls += __shfl_xor(ls, 2);
            ls += __shfl_xor(ls, 4);
            ls += __shfl_xor(ls, 8);
            lsum[r] = lsum[r] * alpha[r] + ls;
        }
#pragma unroll
        for (int dt = 0; dt < 4; dt++)
#pragma unroll
            for (int r = 0; r < 4; r++) o[dt][r] *= alpha[r];

        // ---- P -> bf16 -> LDS (C-layout -> A-layout) ----
#pragma unroll
        for (int ct = 0; ct < 4; ct++)
#pragma unroll
            for (int r = 0; r < 4; r++)
                Ps[wave][quad * 4 + r][ct * 16 + l16] = f2bf(s[ct][r]);

        bh8 p0 = *(const bh8*)&Ps[wave][l16][quad * 8];
        bh8 p1 = *(const bh8*)&Ps[wave][l16][32 + quad * 8];
#pragma unroll
        for (int dt = 0; dt < 4; dt++) {
            bh8 v0 = *(const bh8*)&Vts[dt * 16 + l16][quad * 8];
            bh8 v1 = *(const bh8*)&Vts[dt * 16 + l16][32 + quad * 8];
            o[dt] = MFMA(p0, v0, o[dt]);
            o[dt] = MFMA(p1, v1, o[dt]);
        }
    }

    // epilogue
#pragma unroll
    for (int r = 0; r < 4; r++) lsum[r] = 1.f / lsum[r];
#pragma unroll
    for (int dt = 0; dt < 4; dt++)
#pragma unroll
        for (int r = 0; r < 4; r++) {
            int row = r0 + wr + quad * 4 + r;
            int col = h * DH + dt * 16 + l16;
            Hc[(size_t)(b * NSEQ + row) * EDIM + col] = f2bf(o[dt][r] * lsum[r]);
        }
}

// ---------------------------------------------------------------------------
// Output projection: out = Hc_bf16 @ WO, 1-term MFMA, quad-major LDS,
// XCD swizzle (6 n-siblings of an A-strip share an XCD).
// ---------------------------------------------------------------------------
__global__ __launch_bounds__(256)
void out_gemm(const unsigned short* __restrict__ A, const unsigned short* __restrict__ Wh,
              float* __restrict__ C)
{
    const int bid = blockIdx.x;                  // [0,384)
    const int xcd = bid & 7, j = bid >> 3;       // j in [0,48)
    const int mblk = xcd * 8 + (j / 6);          // 0..63
    const int nblk = j % 6;

    __shared__ unsigned short Ahq[4][128][8];
    __shared__ unsigned short Bhq[4][128][8];

    const int t = threadIdx.x;
    const int wave = t >> 6, lane = t & 63;
    const int quad = lane >> 4, l16 = lane & 15;
    const int wm = (wave >> 1) * 64, wn = (wave & 1) * 64;
    const int m0 = mblk * 128, n0 = nblk * 128;
    const int sr = t >> 1, q0 = (t & 1) * 2;

    f4 acc[4][4];
#pragma unroll
    for (int i = 0; i < 4; i++)
#pragma unroll
        for (int j2 = 0; j2 < 4; j2++) acc[i][j2] = (f4){0.f, 0.f, 0.f, 0.f};

    for (int k0 = 0; k0 < EDIM; k0 += 32) {
        const size_t ao = (size_t)(m0 + sr) * EDIM + k0 + q0 * 8;
        const size_t bo = (size_t)(n0 + sr) * EDIM + k0 + q0 * 8;
        us8 a0 = *(const us8*)&A[ao], a1 = *(const us8*)&A[ao + 8];
        us8 b0 = *(const us8*)&Wh[bo], b1 = *(const us8*)&Wh[bo + 8];
        __syncthreads();
        *(us8*)&Ahq[q0][sr][0] = a0; *(us8*)&Ahq[q0 + 1][sr][0] = a1;
        *(us8*)&Bhq[q0][sr][0] = b0; *(us8*)&Bhq[q0 + 1][sr][0] = b1;
        __syncthreads();

        bh8 aF[4], bF[4];
#pragma unroll
        for (int mt = 0; mt < 4; mt++)
            aF[mt] = *(const bh8*)&Ahq[quad][wm + mt * 16 + l16][0];
#pragma unroll
        for (int nt = 0; nt < 4; nt++)
            bF[nt] = *(const bh8*)&Bhq[quad][wn + nt * 16 + l16][0];
#pragma unroll
        for (int mt = 0; mt < 4; mt++)
#pragma unroll
            for (int nt = 0; nt < 4; nt++)
                acc[mt][nt] = MFMA(aF[mt], bF[nt], acc[mt][nt]);
    }

#pragma unroll
    for (int mt = 0; mt < 4; mt++)
#pragma unroll
        for (int nt = 0; nt < 4; nt++)
#pragma unroll
            for (int r = 0; r < 4; r++) {
                int row = m0 + wm + mt * 16 + quad * 4 + r;
                int col = n0 + wn + nt * 16 + l16;
                C[(size_t)row * EDIM + col] = acc[mt][nt][r];
            }
}

// ---------------------------------------------------------------------------
extern "C" void kernel_launch(void* const* d_in, const int* in_sizes, int n_in,
                              void* d_out, int out_size, void* d_ws, size_t ws_size,
                              hipStream_t stream)
{
    const float* emb = (const float*)d_in[0];
    const float* Bm  = (const float*)d_in[1];
    const float* WQ  = (const float*)d_in[2];
    const float* WK  = (const float*)d_in[3];
    const float* WV  = (const float*)d_in[4];
    const float* WO  = (const float*)d_in[5];
    float* out = (float*)d_out;

    const size_t SZ = (size_t)NB * NSEQ * EDIM;        // 6,291,456 elements
    const size_t WSZ = (size_t)EDIM * EDIM;            // 589,824

    unsigned short* p  = (unsigned short*)d_ws;
    unsigned short* Eh = p;                  p += SZ;   // later reused as Hc
    unsigned short* El = p;                  p += SZ;
    unsigned short* Wb = p;                  p += 8 * WSZ;  // WQ h/l, WK h/l, WV h/l, WO h/l
    unsigned short* Qh = p;                  p += SZ;
    unsigned short* Ql = p;                  p += SZ;
    unsigned short* Kh = p;                  p += SZ;
    unsigned short* Kl = p;                  p += SZ;
    unsigned short* Vt = p;                  p += SZ;
    unsigned short* Hc = Eh;                 // alias: emb-hi dead after qkv_gemm

    // 1) conversions
    conv_emb<<<dim3(SZ / (256 * 4)), dim3(256), 0, stream>>>(emb, Eh, El);
    conv_w<<<dim3(EDIM / 64, EDIM / 64, 4), dim3(256), 0, stream>>>(WQ, WK, WV, WO, Wb);

    // 2) QKV projection (Q/K 3-term, V 1-term), XCD-swizzled 1D grid
    qkv_gemm<<<dim3(1152), dim3(256), 0, stream>>>(
        Eh, El, Wb, Qh, Ql, Kh, Kl, Vt);

    // 3) flash attention, XCD-swizzled 1D grid
    attn_mfma<<<dim3(1536), dim3(256), 0, stream>>>(
        Qh, Ql, Kh, Kl, Vt, Bm, Hc);

    // 4) output projection, XCD-swizzled 1D grid
    out_gemm<<<dim3(384), dim3(256), 0, stream>>>(
        Hc, Wb + 6 * WSZ, out);
}

// Round 7
// 337.406 us; speedup vs baseline: 1.2218x; 1.2218x over previous
//
#include <hip/hip_runtime.h>
#include <math.h>

#define EDIM 768
#define NSEQ 1024
#define NB 8
#define NH 12
#define DH 64

typedef __attribute__((ext_vector_type(8))) short bh8;       // 8 bf16 (4 VGPRs) MFMA frag
typedef __attribute__((ext_vector_type(4))) float f4;        // MFMA acc
typedef __attribute__((ext_vector_type(8))) unsigned short us8;
typedef __attribute__((ext_vector_type(4))) unsigned short us4;

#define MFMA(a, b, c) __builtin_amdgcn_mfma_f32_16x16x32_bf16((bh8)(a), (bh8)(b), (c), 0, 0, 0)

__device__ __forceinline__ unsigned short f2bf(float x) {
    union { float f; unsigned u; } v; v.f = x;
    unsigned r = v.u + 0x7fff + ((v.u >> 16) & 1);   // round-to-nearest-even
    return (unsigned short)(r >> 16);
}
__device__ __forceinline__ float bf2f(unsigned short b) {
    union { float f; unsigned u; } v; v.u = ((unsigned)b) << 16;
    return v.f;
}

// DPP row (16-lane) rotate: VALU-pipe cross-lane, no LDS involvement.
template <int C>
__device__ __forceinline__ float dppmov(float x) {
    union { int i; float f; } u; u.f = x;
    u.i = __builtin_amdgcn_update_dpp(0, u.i, C, 0xF, 0xF, true);
    return u.f;
}
// full reduction over the 16-lane DPP row (= the l16 group, since lane = quad*16+l16)
__device__ __forceinline__ float rowmax16(float x) {
    x = fmaxf(x, dppmov<0x121>(x));   // ror:1
    x = fmaxf(x, dppmov<0x122>(x));   // ror:2
    x = fmaxf(x, dppmov<0x124>(x));   // ror:4
    x = fmaxf(x, dppmov<0x128>(x));   // ror:8
    return x;
}
__device__ __forceinline__ float rowsum16(float x) {
    x += dppmov<0x121>(x);
    x += dppmov<0x122>(x);
    x += dppmov<0x124>(x);
    x += dppmov<0x128>(x);
    return x;
}

// ---------------------------------------------------------------------------
// emb fp32 -> hi/lo bf16
// ---------------------------------------------------------------------------
__global__ __launch_bounds__(256)
void conv_emb(const float* __restrict__ E, unsigned short* __restrict__ Eh,
              unsigned short* __restrict__ El)
{
    size_t idx = ((size_t)blockIdx.x * 256 + threadIdx.x) * 4;
    float4 v = *(const float4*)&E[idx];
    us4 h, l;
    h.x = f2bf(v.x); l.x = f2bf(v.x - bf2f(h.x));
    h.y = f2bf(v.y); l.y = f2bf(v.y - bf2f(h.y));
    h.z = f2bf(v.z); l.z = f2bf(v.z - bf2f(h.z));
    h.w = f2bf(v.w); l.w = f2bf(v.w - bf2f(h.w));
    *(us4*)&Eh[idx] = h;
    *(us4*)&El[idx] = l;
}

// ---------------------------------------------------------------------------
// W [768k][768n] fp32 -> Wt [768n][768k] hi/lo bf16 (transposed).
// ---------------------------------------------------------------------------
__global__ __launch_bounds__(256)
void conv_w(const float* __restrict__ W0, const float* __restrict__ W1,
            const float* __restrict__ W2, const float* __restrict__ W3,
            unsigned short* __restrict__ Wbase)
{
    const int z = blockIdx.z;
    const float* __restrict__ W = (z == 0) ? W0 : (z == 1) ? W1 : (z == 2) ? W2 : W3;
    unsigned short* __restrict__ Wh = Wbase + (size_t)z * 2 * (EDIM * EDIM);
    unsigned short* __restrict__ Wl = Wh + (EDIM * EDIM);

    __shared__ float T[64][65];
    const int t = threadIdx.x;
    const int n0 = blockIdx.x * 64, k0 = blockIdx.y * 64;

#pragma unroll
    for (int rr = 0; rr < 4; rr++) {
        int row = rr * 16 + (t >> 4);      // k within tile
        int c4  = (t & 15) * 4;            // n within tile
        float4 v = *(const float4*)&W[(size_t)(k0 + row) * EDIM + n0 + c4];
        T[row][c4 + 0] = v.x; T[row][c4 + 1] = v.y;
        T[row][c4 + 2] = v.z; T[row][c4 + 3] = v.w;
    }
    __syncthreads();
#pragma unroll
    for (int rr = 0; rr < 4; rr++) {
        int nn = rr * 16 + (t >> 4);       // n within tile
        int k4 = (t & 15) * 4;             // k within tile
        us4 h, l;
        float v0 = T[k4 + 0][nn], v1 = T[k4 + 1][nn],
              v2 = T[k4 + 2][nn], v3 = T[k4 + 3][nn];
        h.x = f2bf(v0); l.x = f2bf(v0 - bf2f(h.x));
        h.y = f2bf(v1); l.y = f2bf(v1 - bf2f(h.y));
        h.z = f2bf(v2); l.z = f2bf(v2 - bf2f(h.z));
        h.w = f2bf(v3); l.w = f2bf(v3 - bf2f(h.w));
        size_t o = (size_t)(n0 + nn) * EDIM + k0 + k4;
        *(us4*)&Wh[o] = h;
        *(us4*)&Wl[o] = l;
    }
}

// ---------------------------------------------------------------------------
// QKV projection, split-bf16 MFMA, quad-major LDS, XCD-swizzled.
// Software-pipelined: next k-tile's global loads are issued AFTER barrier 2,
// so they fly during the MFMA section and are complete when the next
// iteration's barrier-1 vmcnt(0) drain hits.
// z=0 (Q), z=1 (K): 3-term hi/lo. z=2 (V): 1-term.
// ---------------------------------------------------------------------------
__global__ __launch_bounds__(256)
void qkv_gemm(const unsigned short* __restrict__ Eh, const unsigned short* __restrict__ El,
              const unsigned short* __restrict__ Wbase,
              unsigned short* __restrict__ Qh, unsigned short* __restrict__ Ql,
              unsigned short* __restrict__ Kh, unsigned short* __restrict__ Kl,
              unsigned short* __restrict__ Vt)
{
    const int bid = blockIdx.x;
    const int xcd = bid & 7, j = bid >> 3;        // j in [0,144)
    const int mblk = xcd * 8 + (j / 18);          // 0..63
    const int rest = j % 18;
    const int nblk = rest % 6, z = rest / 6;

    const unsigned short* __restrict__ Wh = Wbase + (size_t)z * 2 * (EDIM * EDIM);
    const unsigned short* __restrict__ Wl = Wh + (EDIM * EDIM);

    __shared__ unsigned short Ahq[4][128][8], Alq[4][128][8];
    __shared__ unsigned short Bhq[4][128][8], Blq[4][128][8];

    const int t = threadIdx.x;
    const int wave = t >> 6, lane = t & 63;
    const int quad = lane >> 4, l16 = lane & 15;
    const int wm = (wave >> 1) * 64, wn = (wave & 1) * 64;
    const int m0 = mblk * 128, n0 = nblk * 128;

    const int sr = t >> 1, q0 = (t & 1) * 2;   // staging: row, first quad

    f4 acc[4][4];
#pragma unroll
    for (int i = 0; i < 4; i++)
#pragma unroll
        for (int j2 = 0; j2 < 4; j2++) acc[i][j2] = (f4){0.f, 0.f, 0.f, 0.f};

    const size_t abase = (size_t)(m0 + sr) * EDIM + q0 * 8;
    const size_t bbase = (size_t)(n0 + sr) * EDIM + q0 * 8;

    // preload tile 0
    us8 a0 = *(const us8*)&Eh[abase], a1 = *(const us8*)&Eh[abase + 8];
    us8 b0 = *(const us8*)&Wh[bbase], b1 = *(const us8*)&Wh[bbase + 8];
    us8 a2, a3, b2, b3;
    if (z != 2) {
        a2 = *(const us8*)&El[abase]; a3 = *(const us8*)&El[abase + 8];
        b2 = *(const us8*)&Wl[bbase]; b3 = *(const us8*)&Wl[bbase + 8];
    }

    for (int it = 0; it < 24; it++) {
        __syncthreads();          // prev tile consumed; drains prefetch vmcnt
        *(us8*)&Ahq[q0][sr][0] = a0; *(us8*)&Ahq[q0 + 1][sr][0] = a1;
        *(us8*)&Bhq[q0][sr][0] = b0; *(us8*)&Bhq[q0 + 1][sr][0] = b1;
        if (z != 2) {
            *(us8*)&Alq[q0][sr][0] = a2; *(us8*)&Alq[q0 + 1][sr][0] = a3;
            *(us8*)&Blq[q0][sr][0] = b2; *(us8*)&Blq[q0 + 1][sr][0] = b3;
        }
        __syncthreads();

        // issue next tile's loads (wrapped; in flight across the MFMA section)
        {
            const int kn = (it < 23) ? (it + 1) * 32 : 0;
            a0 = *(const us8*)&Eh[abase + kn]; a1 = *(const us8*)&Eh[abase + kn + 8];
            b0 = *(const us8*)&Wh[bbase + kn]; b1 = *(const us8*)&Wh[bbase + kn + 8];
            if (z != 2) {
                a2 = *(const us8*)&El[abase + kn]; a3 = *(const us8*)&El[abase + kn + 8];
                b2 = *(const us8*)&Wl[bbase + kn]; b3 = *(const us8*)&Wl[bbase + kn + 8];
            }
        }

        bh8 aH[4], bH[4];
#pragma unroll
        for (int mt = 0; mt < 4; mt++)
            aH[mt] = *(const bh8*)&Ahq[quad][wm + mt * 16 + l16][0];
#pragma unroll
        for (int nt = 0; nt < 4; nt++)
            bH[nt] = *(const bh8*)&Bhq[quad][wn + nt * 16 + l16][0];

        if (z != 2) {
            bh8 aL[4], bL[4];
#pragma unroll
            for (int mt = 0; mt < 4; mt++)
                aL[mt] = *(const bh8*)&Alq[quad][wm + mt * 16 + l16][0];
#pragma unroll
            for (int nt = 0; nt < 4; nt++)
                bL[nt] = *(const bh8*)&Blq[quad][wn + nt * 16 + l16][0];
#pragma unroll
            for (int mt = 0; mt < 4; mt++)
#pragma unroll
                for (int nt = 0; nt < 4; nt++) {
                    acc[mt][nt] = MFMA(aH[mt], bH[nt], acc[mt][nt]);
                    acc[mt][nt] = MFMA(aH[mt], bL[nt], acc[mt][nt]);
                    acc[mt][nt] = MFMA(aL[mt], bH[nt], acc[mt][nt]);
                }
        } else {
#pragma unroll
            for (int mt = 0; mt < 4; mt++)
#pragma unroll
                for (int nt = 0; nt < 4; nt++)
                    acc[mt][nt] = MFMA(aH[mt], bH[nt], acc[mt][nt]);
        }
    }

    // epilogue: C/D layout col=lane&15, row=quad*4+reg
#pragma unroll
    for (int mt = 0; mt < 4; mt++)
#pragma unroll
        for (int nt = 0; nt < 4; nt++)
#pragma unroll
            for (int r = 0; r < 4; r++) {
                int row = m0 + wm + mt * 16 + quad * 4 + r;
                int col = n0 + wn + nt * 16 + l16;
                float v = acc[mt][nt][r];
                if (z == 2) {
                    int bb = row >> 10, nr = row & 1023;
                    int g = nr * 12 + (col >> 6);          // 768 = 12*64
                    int hh = g >> 10, key = g & 1023, dim = col & 63;
                    Vt[(((size_t)(bb * NH + hh)) * DH + dim) * NSEQ + key] = f2bf(v);
                } else {
                    unsigned short h = f2bf(v);
                    unsigned short l = f2bf(v - bf2f(h));
                    size_t o = (size_t)row * EDIM + col;
                    if (z == 0) { Qh[o] = h; Ql[o] = l; }
                    else        { Kh[o] = h; Kl[o] = l; }
                }
            }
}

// ---------------------------------------------------------------------------
// Flash attention, MFMA, XCD-swizzled. Round-7 changes:
//  - software-pipelined K/V staging (prefetch issued after barrier 2 -> in
//    flight across the whole compute body; the vmcnt(0) drain at the next
//    barrier finds it complete)
//  - DPP ROW_ROR reductions for softmax max/sum (VALU pipe, not LDS)
//  - bias loads hoisted to the top of the compute section
// ---------------------------------------------------------------------------
__global__ __launch_bounds__(256)
void attn_mfma(const unsigned short* __restrict__ Qh, const unsigned short* __restrict__ Ql,
               const unsigned short* __restrict__ Kh, const unsigned short* __restrict__ Kl,
               const unsigned short* __restrict__ Vt, const float* __restrict__ Bm,
               unsigned short* __restrict__ Hc)
{
    const int bid = blockIdx.x;
    const int xcd = bid & 7, j = bid >> 3;        // j in [0,192)
    const int combo = xcd * 12 + (j >> 4);        // 0..95, consecutive = same h
    const int rt = j & 15;
    const int h = combo >> 3, b = combo & 7;
    const int r0 = rt * 64;

    __shared__ unsigned short Khs[64][72], Kls[64][72];   // also Q staging
    __shared__ unsigned short Vts[64][72];                // [dim][key]
    __shared__ unsigned short Ps[4][16][68];              // 2-way write pattern

    const int t = threadIdx.x;
    const int wave = t >> 6, lane = t & 63;
    const int quad = lane >> 4, l16 = lane & 15;
    const int wr = wave * 16;

    const int srow = t >> 2, sseg = (t & 3) * 16;

    const size_t hb = (size_t)b * (NSEQ * EDIM) + (size_t)h * (NSEQ * DH);
    const size_t vb = (((size_t)(b * NH + h)) * DH) * NSEQ;

    const size_t kbase = hb + (size_t)srow * DH + sseg;
    const size_t vbase = vb + (size_t)srow * NSEQ + sseg;

    // ---- stage Q through the K buffers, pull frags to registers ----
    bh8 qfh[2], qfl[2];
    {
        const size_t qo = hb + (size_t)(r0 + srow) * DH + sseg;
        us8 q0 = *(const us8*)&Qh[qo], q1 = *(const us8*)&Qh[qo + 8];
        us8 q2 = *(const us8*)&Ql[qo], q3 = *(const us8*)&Ql[qo + 8];
        *(us8*)&Khs[srow][sseg] = q0; *(us8*)&Khs[srow][sseg + 8] = q1;
        *(us8*)&Kls[srow][sseg] = q2; *(us8*)&Kls[srow][sseg + 8] = q3;
        __syncthreads();
#pragma unroll
        for (int ks = 0; ks < 2; ks++) {
            qfh[ks] = *(const bh8*)&Khs[wr + l16][ks * 32 + quad * 8];
            qfl[ks] = *(const bh8*)&Kls[wr + l16][ks * 32 + quad * 8];
        }
    }

    // preload tile 0 staging regs
    us8 k0v = *(const us8*)&Kh[kbase],     k1v = *(const us8*)&Kh[kbase + 8];
    us8 k2v = *(const us8*)&Kl[kbase],     k3v = *(const us8*)&Kl[kbase + 8];
    us8 v0v = *(const us8*)&Vt[vbase],     v1v = *(const us8*)&Vt[vbase + 8];

    float m[4] = {-3e38f, -3e38f, -3e38f, -3e38f};
    float lsum[4] = {0.f, 0.f, 0.f, 0.f};
    f4 o[4];
#pragma unroll
    for (int dt = 0; dt < 4; dt++) o[dt] = (f4){0.f, 0.f, 0.f, 0.f};

    const float* bb = Bm + ((size_t)h << 20) + ((size_t)(r0 + wr + quad * 4) << 10) + l16;

    for (int kt = 0; kt < 16; kt++) {
        const int c0 = kt * 64;
        __syncthreads();   // prev tile consumed (+ Q frags read at kt=0); drains prefetch
        *(us8*)&Khs[srow][sseg] = k0v; *(us8*)&Khs[srow][sseg + 8] = k1v;
        *(us8*)&Kls[srow][sseg] = k2v; *(us8*)&Kls[srow][sseg + 8] = k3v;
        *(us8*)&Vts[srow][sseg] = v0v; *(us8*)&Vts[srow][sseg + 8] = v1v;
        __syncthreads();

        // issue next tile's staging loads (in flight across the compute body)
        {
            const int cn = ((kt + 1) & 15) * 64;
            k0v = *(const us8*)&Kh[kbase + (size_t)cn * DH];
            k1v = *(const us8*)&Kh[kbase + (size_t)cn * DH + 8];
            k2v = *(const us8*)&Kl[kbase + (size_t)cn * DH];
            k3v = *(const us8*)&Kl[kbase + (size_t)cn * DH + 8];
            v0v = *(const us8*)&Vt[vbase + cn];
            v1v = *(const us8*)&Vt[vbase + cn + 8];
        }

        // bias loads for this tile (issued early, consumed after the MFMAs)
        float bv[4][4];
#pragma unroll
        for (int ct = 0; ct < 4; ct++)
#pragma unroll
            for (int r = 0; r < 4; r++)
                bv[ct][r] = bb[(size_t)r * NSEQ + c0 + ct * 16];

        // ---- scores ----
        f4 s[4];
#pragma unroll
        for (int ct = 0; ct < 4; ct++) {
            bh8 kh0 = *(const bh8*)&Khs[ct * 16 + l16][quad * 8];
            bh8 kh1 = *(const bh8*)&Khs[ct * 16 + l16][32 + quad * 8];
            bh8 kl0 = *(const bh8*)&Kls[ct * 16 + l16][quad * 8];
            bh8 kl1 = *(const bh8*)&Kls[ct * 16 + l16][32 + quad * 8];
            f4 a = (f4){0.f, 0.f, 0.f, 0.f};
            a = MFMA(qfh[0], kh0, a); a = MFMA(qfh[1], kh1, a);
            a = MFMA(qfl[0], kh0, a); a = MFMA(qfl[1], kh1, a);
            a = MFMA(qfh[0], kl0, a); a = MFMA(qfh[1], kl1, a);
            s[ct] = a;
        }
#pragma unroll
        for (int ct = 0; ct < 4; ct++)
#pragma unroll
            for (int r = 0; r < 4; r++)
                s[ct][r] = fmaf(s[ct][r], 0.125f, bv[ct][r]);

        // ---- online softmax (DPP row reductions over the 16 l16 lanes) ----
        float alpha[4];
#pragma unroll
        for (int r = 0; r < 4; r++) {
            float mx = fmaxf(fmaxf(s[0][r], s[1][r]), fmaxf(s[2][r], s[3][r]));
            mx = rowmax16(mx);
            float mn = fmaxf(m[r], mx);
            alpha[r] = __expf(m[r] - mn);
            m[r] = mn;
        }
#pragma unroll
        for (int ct = 0; ct < 4; ct++)
#pragma unroll
            for (int r = 0; r < 4; r++)
                s[ct][r] = __expf(s[ct][r] - m[r]);
#pragma unroll
        for (int r = 0; r < 4; r++) {
            float ls = rowsum16(s[0][r] + s[1][r] + s[2][r] + s[3][r]);
            lsum[r] = lsum[r] * alpha[r] + ls;
        }
#pragma unroll
        for (int dt = 0; dt < 4; dt++)
#pragma unroll
            for (int r = 0; r < 4; r++) o[dt][r] *= alpha[r];

        // ---- P -> bf16 -> LDS (C-layout -> A-layout) ----
#pragma unroll
        for (int ct = 0; ct < 4; ct++)
#pragma unroll
            for (int r = 0; r < 4; r++)
                Ps[wave][quad * 4 + r][ct * 16 + l16] = f2bf(s[ct][r]);

        bh8 p0 = *(const bh8*)&Ps[wave][l16][quad * 8];
        bh8 p1 = *(const bh8*)&Ps[wave][l16][32 + quad * 8];
#pragma unroll
        for (int dt = 0; dt < 4; dt++) {
            bh8 v0 = *(const bh8*)&Vts[dt * 16 + l16][quad * 8];
            bh8 v1 = *(const bh8*)&Vts[dt * 16 + l16][32 + quad * 8];
            o[dt] = MFMA(p0, v0, o[dt]);
            o[dt] = MFMA(p1, v1, o[dt]);
        }
    }

    // epilogue
#pragma unroll
    for (int r = 0; r < 4; r++) lsum[r] = 1.f / lsum[r];
#pragma unroll
    for (int dt = 0; dt < 4; dt++)
#pragma unroll
        for (int r = 0; r < 4; r++) {
            int row = r0 + wr + quad * 4 + r;
            int col = h * DH + dt * 16 + l16;
            Hc[(size_t)(b * NSEQ + row) * EDIM + col] = f2bf(o[dt][r] * lsum[r]);
        }
}

// ---------------------------------------------------------------------------
// Output projection: out = Hc_bf16 @ WO, 1-term MFMA, quad-major LDS,
// XCD-swizzled, software-pipelined staging.
// ---------------------------------------------------------------------------
__global__ __launch_bounds__(256)
void out_gemm(const unsigned short* __restrict__ A, const unsigned short* __restrict__ Wh,
              float* __restrict__ C)
{
    const int bid = blockIdx.x;                  // [0,384)
    const int xcd = bid & 7, j = bid >> 3;       // j in [0,48)
    const int mblk = xcd * 8 + (j / 6);          // 0..63
    const int nblk = j % 6;

    __shared__ unsigned short Ahq[4][128][8];
    __shared__ unsigned short Bhq[4][128][8];

    const int t = threadIdx.x;
    const int wave = t >> 6, lane = t & 63;
    const int quad = lane >> 4, l16 = lane & 15;
    const int wm = (wave >> 1) * 64, wn = (wave & 1) * 64;
    const int m0 = mblk * 128, n0 = nblk * 128;
    const int sr = t >> 1, q0 = (t & 1) * 2;

    f4 acc[4][4];
#pragma unroll
    for (int i = 0; i < 4; i++)
#pragma unroll
        for (int j2 = 0; j2 < 4; j2++) acc[i][j2] = (f4){0.f, 0.f, 0.f, 0.f};

    const size_t abase = (size_t)(m0 + sr) * EDIM + q0 * 8;
    const size_t bbase = (size_t)(n0 + sr) * EDIM + q0 * 8;

    us8 a0 = *(const us8*)&A[abase],  a1 = *(const us8*)&A[abase + 8];
    us8 b0 = *(const us8*)&Wh[bbase], b1 = *(const us8*)&Wh[bbase + 8];

    for (int it = 0; it < 24; it++) {
        __syncthreads();
        *(us8*)&Ahq[q0][sr][0] = a0; *(us8*)&Ahq[q0 + 1][sr][0] = a1;
        *(us8*)&Bhq[q0][sr][0] = b0; *(us8*)&Bhq[q0 + 1][sr][0] = b1;
        __syncthreads();

        {
            const int kn = (it < 23) ? (it + 1) * 32 : 0;
            a0 = *(const us8*)&A[abase + kn];  a1 = *(const us8*)&A[abase + kn + 8];
            b0 = *(const us8*)&Wh[bbase + kn]; b1 = *(const us8*)&Wh[bbase + kn + 8];
        }

        bh8 aF[4], bF[4];
#pragma unroll
        for (int mt = 0; mt < 4; mt++)
            aF[mt] = *(const bh8*)&Ahq[quad][wm + mt * 16 + l16][0];
#pragma unroll
        for (int nt = 0; nt < 4; nt++)
            bF[nt] = *(const bh8*)&Bhq[quad][wn + nt * 16 + l16][0];
#pragma unroll
        for (int mt = 0; mt < 4; mt++)
#pragma unroll
            for (int nt = 0; nt < 4; nt++)
                acc[mt][nt] = MFMA(aF[mt], bF[nt], acc[mt][nt]);
    }

#pragma unroll
    for (int mt = 0; mt < 4; mt++)
#pragma unroll
        for (int nt = 0; nt < 4; nt++)
#pragma unroll
            for (int r = 0; r < 4; r++) {
                int row = m0 + wm + mt * 16 + quad * 4 + r;
                int col = n0 + wn + nt * 16 + l16;
                C[(size_t)row * EDIM + col] = acc[mt][nt][r];
            }
}

// ---------------------------------------------------------------------------
extern "C" void kernel_launch(void* const* d_in, const int* in_sizes, int n_in,
                              void* d_out, int out_size, void* d_ws, size_t ws_size,
                              hipStream_t stream)
{
    const float* emb = (const float*)d_in[0];
    const float* Bm  = (const float*)d_in[1];
    const float* WQ  = (const float*)d_in[2];
    const float* WK  = (const float*)d_in[3];
    const float* WV  = (const float*)d_in[4];
    const float* WO  = (const float*)d_in[5];
    float* out = (float*)d_out;

    const size_t SZ = (size_t)NB * NSEQ * EDIM;        // 6,291,456 elements
    const size_t WSZ = (size_t)EDIM * EDIM;            // 589,824

    unsigned short* p  = (unsigned short*)d_ws;
    unsigned short* Eh = p;                  p += SZ;   // later reused as Hc
    unsigned short* El = p;                  p += SZ;
    unsigned short* Wb = p;                  p += 8 * WSZ;  // WQ h/l, WK h/l, WV h/l, WO h/l
    unsigned short* Qh = p;                  p += SZ;
    unsigned short* Ql = p;                  p += SZ;
    unsigned short* Kh = p;                  p += SZ;
    unsigned short* Kl = p;                  p += SZ;
    unsigned short* Vt = p;                  p += SZ;
    unsigned short* Hc = Eh;                 // alias: emb-hi dead after qkv_gemm

    // 1) conversions
    conv_emb<<<dim3(SZ / (256 * 4)), dim3(256), 0, stream>>>(emb, Eh, El);
    conv_w<<<dim3(EDIM / 64, EDIM / 64, 4), dim3(256), 0, stream>>>(WQ, WK, WV, WO, Wb);

    // 2) QKV projection (Q/K 3-term, V 1-term), XCD-swizzled, pipelined
    qkv_gemm<<<dim3(1152), dim3(256), 0, stream>>>(
        Eh, El, Wb, Qh, Ql, Kh, Kl, Vt);

    // 3) flash attention, XCD-swizzled, pipelined, DPP softmax
    attn_mfma<<<dim3(1536), dim3(256), 0, stream>>>(
        Qh, Ql, Kh, Kl, Vt, Bm, Hc);

    // 4) output projection, XCD-swizzled, pipelined
    out_gemm<<<dim3(384), dim3(256), 0, stream>>>(
        Hc, Wb + 6 * WSZ, out);
}